// Round 2
// baseline (181.069 us; speedup 1.0000x reference)
//
#include <hip/hip_runtime.h>
#include <hip/hip_bf16.h>

// SpherePool: out[bt, o, c] = max_{k<7} tensor[bt, index[o,k], c]
// B*T = 16, N = 40962, C = 256, N_OUT = 10242, K = 7.
// Memory-bound gather + row-max.
//   - 1 output row = 256 f32 = 64 lanes x float4 (fully coalesced, 1KB/row).
//   - 2 rows per WAVE -> 14 independent gather loads in flight (latency hiding).
//   - Non-temporal output stores: the 168 MB output stream never gets re-read;
//     keeping it out of L2/L3 preserves Infinity-Cache residency of the 42 MB
//     per-bt gather slice (reuse factor ~1.75x).
//   - Grid ordered o-fastest so concurrent blocks share one bt slice in L3.

#define N_IN    40962
#define N_OUT   10242
#define KGATH   7
#define C_VEC   64          // 256 f32 channels / 4 per float4
#define ROWS_PER_BLOCK 8    // 4 waves x 2 rows

typedef float f32x4 __attribute__((ext_vector_type(4)));

__device__ __forceinline__ f32x4 vmax4(f32x4 a, f32x4 b) {
    f32x4 r;
    r.x = fmaxf(a.x, b.x);
    r.y = fmaxf(a.y, b.y);
    r.z = fmaxf(a.z, b.z);
    r.w = fmaxf(a.w, b.w);
    return r;
}

__global__ __launch_bounds__(256) void spherepool_kernel(
    const f32x4* __restrict__ tensor,   // [BT][N_IN][64] f32x4
    const int*   __restrict__ index,    // [N_OUT][7]
    f32x4*       __restrict__ out)      // [BT][N_OUT][64] f32x4
{
    const int wave = threadIdx.x >> 6;
    const int lane = threadIdx.x & 63;

    const int row0 = blockIdx.x * ROWS_PER_BLOCK + wave * 2;   // even
    // row0,row0+1 never straddle a bt boundary (boundary offset 10241 is odd).
    const int bt = row0 / N_OUT;
    const int o0 = row0 - bt * N_OUT;

    const int* idx0 = index + (size_t)o0 * KGATH;
    const int* idx1 = idx0 + KGATH;
    const f32x4* __restrict__ base = tensor + (size_t)bt * N_IN * C_VEC;

    // 14 independent gathers; each wave access is 64 x 16B contiguous (1KB).
    f32x4 a0 = base[(size_t)idx0[0] * C_VEC + lane];
    f32x4 a1 = base[(size_t)idx0[1] * C_VEC + lane];
    f32x4 a2 = base[(size_t)idx0[2] * C_VEC + lane];
    f32x4 a3 = base[(size_t)idx0[3] * C_VEC + lane];
    f32x4 a4 = base[(size_t)idx0[4] * C_VEC + lane];
    f32x4 a5 = base[(size_t)idx0[5] * C_VEC + lane];
    f32x4 a6 = base[(size_t)idx0[6] * C_VEC + lane];

    f32x4 b0 = base[(size_t)idx1[0] * C_VEC + lane];
    f32x4 b1 = base[(size_t)idx1[1] * C_VEC + lane];
    f32x4 b2 = base[(size_t)idx1[2] * C_VEC + lane];
    f32x4 b3 = base[(size_t)idx1[3] * C_VEC + lane];
    f32x4 b4 = base[(size_t)idx1[4] * C_VEC + lane];
    f32x4 b5 = base[(size_t)idx1[5] * C_VEC + lane];
    f32x4 b6 = base[(size_t)idx1[6] * C_VEC + lane];

    f32x4 m0 = vmax4(vmax4(vmax4(a0, a1), vmax4(a2, a3)),
                     vmax4(vmax4(a4, a5), a6));
    f32x4 m1 = vmax4(vmax4(vmax4(b0, b1), vmax4(b2, b3)),
                     vmax4(vmax4(b4, b5), b6));

    __builtin_nontemporal_store(m0, &out[(size_t)row0 * C_VEC + lane]);
    __builtin_nontemporal_store(m1, &out[(size_t)(row0 + 1) * C_VEC + lane]);
}

extern "C" void kernel_launch(void* const* d_in, const int* in_sizes, int n_in,
                              void* d_out, int out_size, void* d_ws, size_t ws_size,
                              hipStream_t stream) {
    const f32x4* tensor = (const f32x4*)d_in[0];
    const int*   index  = (const int*)d_in[1];
    f32x4*       out    = (f32x4*)d_out;

    const int total_rows = 16 * N_OUT;               // 163872, divisible by 8
    const int blocks = total_rows / ROWS_PER_BLOCK;  // 20484

    spherepool_kernel<<<blocks, 256, 0, stream>>>(tensor, index, out);
}